// Round 4
// baseline (344.720 us; speedup 1.0000x reference)
//
#include <hip/hip_runtime.h>
#include <cstdint>
#include <cstddef>

#define N_    32
#define C_    256
#define H_    56
#define W_    56
#define HW_   (H_ * W_)      // 3136
#define NHW_  (N_ * HW_)     // 100352
#define COUT_ 256
#define EPS_  1e-4f
#define PW_   58             // padded width
#define PIMG_ (PW_ * PW_)    // 3364 padded pixels per image
#define TPX_  32             // pixels per k_conv block

// ---------------------------------------------------------------------------
// Kernel 1a: BN partial sums. 2048 blocks = (c, slice of 4 images).
// ---------------------------------------------------------------------------
__global__ void k_bn_partial(const float* __restrict__ x,
                             float* __restrict__ ps, float* __restrict__ pq) {
    const int c = blockIdx.x >> 3;
    const int s = blockIdx.x & 7;
    const int t = threadIdx.x;
    float sm = 0.f, sq = 0.f;
    for (int n = s * 4; n < s * 4 + 4; ++n) {
        const float4* p = (const float4*)(x + (size_t)(n * C_ + c) * HW_);
        for (int i = t; i < HW_ / 4; i += 256) {
            float4 v = p[i];
            sm += v.x + v.y + v.z + v.w;
            sq += v.x * v.x + v.y * v.y + v.z * v.z + v.w * v.w;
        }
    }
    __shared__ float ls[256], lq[256];
    ls[t] = sm; lq[t] = sq;
    __syncthreads();
    for (int off = 128; off >= 1; off >>= 1) {
        if (t < off) { ls[t] += ls[t + off]; lq[t] += lq[t + off]; }
        __syncthreads();
    }
    if (t == 0) { ps[s * C_ + c] = ls[0]; pq[s * C_ + c] = lq[0]; }
}

// ---------------------------------------------------------------------------
// Kernel 1b: finalize per-channel affine: xn = x*a[c] + bb[c]
// ---------------------------------------------------------------------------
__global__ void k_bn_final(const float* __restrict__ ps, const float* __restrict__ pq,
                           const float* __restrict__ gamma, const float* __restrict__ beta,
                           float* __restrict__ a, float* __restrict__ bb) {
    const int c = threadIdx.x;
    float sm = 0.f, sq = 0.f;
    for (int s = 0; s < 8; ++s) { sm += ps[s * C_ + c]; sq += pq[s * C_ + c]; }
    float mu   = sm * (1.f / NHW_);
    float var  = sq * (1.f / NHW_) - mu * mu;
    float rstd = rsqrtf(var + EPS_);
    float g    = gamma[c] * rstd;
    a[c]  = g;
    bb[c] = beta[c] - mu * g;
}

// ---------------------------------------------------------------------------
// Kernel 2: weight prep. alpha, bit-pack sign(W), and border-correction table
// ctab[cls][co] = sum over invalid taps of (2*P[t] - 256), cls = rowcls*3+colcls.
// With zero-padded xbits, dot = 2304 - 2*acc + ctab[cls][co].
// ---------------------------------------------------------------------------
__global__ void k_wpack(const float* __restrict__ Wt, float* __restrict__ alpha,
                        uint64_t* __restrict__ wbits, int* __restrict__ ctab) {
    const int co = blockIdx.x;
    const int ci = threadIdx.x;
    const int lane = ci & 63, wave = ci >> 6;
    const float* p = Wt + (size_t)(co * C_ + ci) * 9;
    float wv[9];
    float asum = 0.f;
#pragma unroll
    for (int t = 0; t < 9; ++t) { wv[t] = p[t]; asum += fabsf(wv[t]); }
    __shared__ int Pl[9];
    if (ci < 9) Pl[ci] = 0;
    __syncthreads();
#pragma unroll
    for (int t = 0; t < 9; ++t) {
        uint64_t mask = __ballot(wv[t] > 0.f);
        if (lane == 0) {
            wbits[(co * 9 + t) * 4 + wave] = mask;
            atomicAdd(&Pl[t], (int)__popcll(mask));
        }
    }
    __shared__ float red[256];
    red[ci] = asum;
    __syncthreads();                       // also publishes Pl
    for (int off = 128; off >= 1; off >>= 1) {
        if (ci < off) red[ci] += red[ci + off];
        __syncthreads();
    }
    if (ci == 0) alpha[co] = red[0] * (1.f / 2304.f);
    if (ci < 9) {
        const int rc = ci / 3, cc = ci % 3;
        unsigned m9 = (rc == 0 ? 0x007u : 0u) | (rc == 2 ? 0x1C0u : 0u)
                    | (cc == 0 ? 0x049u : 0u) | (cc == 2 ? 0x124u : 0u);
        int s = 0;
#pragma unroll
        for (int t = 0; t < 9; ++t)
            if ((m9 >> t) & 1) s += 2 * Pl[t] - 256;
        ctab[ci * 256 + co] = s;
    }
}

// ---------------------------------------------------------------------------
// Kernel 3: fused normalize + |xn| channel-mean + sign bit-pack into PADDED
// layout. lane = pixel (64/block), wave = channel word (4/block). 1568 blocks
// (4x the old parallelism); 64-deep chains split into 4 accumulators.
// ---------------------------------------------------------------------------
__global__ void k_mpack(const float* __restrict__ x, const float* __restrict__ a,
                        const float* __restrict__ bb, uint64_t* __restrict__ xbits,
                        float* __restrict__ m) {
    const int lane = (int)(threadIdx.x & 63);
    const int wd   = (int)(threadIdx.x >> 6);
    const int p  = blockIdx.x * 64 + lane;
    const int n  = p / HW_;
    const int hw = p - n * HW_;
    const int h  = hw / W_;
    const int w  = hw - h * W_;
    const float* xp = x + ((size_t)(n * C_ + wd * 64)) * HW_ + hw;
    float m0 = 0.f, m1 = 0.f, m2 = 0.f, m3 = 0.f;
    uint64_t bw = 0;
#pragma unroll
    for (int j = 0; j < 64; j += 4) {
#pragma unroll
        for (int k = 0; k < 4; ++k) {
            const int c = wd * 64 + j + k;
            float xn = fmaf(xp[(size_t)(j + k) * HW_], a[c], bb[c]);
            if (k == 0) m0 += fabsf(xn); else if (k == 1) m1 += fabsf(xn);
            else if (k == 2) m2 += fabsf(xn); else m3 += fabsf(xn);
            bw |= (xn > 0.f) ? (1ull << (j + k)) : 0ull;
        }
    }
    xbits[((size_t)n * PIMG_ + (size_t)(h + 1) * PW_ + (w + 1)) * 4 + wd] = bw;
    __shared__ float ms[4][64];
    ms[wd][lane] = (m0 + m1) + (m2 + m3);
    __syncthreads();
    if (threadIdx.x < 64) {
        float s = (ms[0][lane] + ms[1][lane]) + (ms[2][lane] + ms[3][lane]);
        m[p] = s * (1.f / C_);
    }
}

// ---------------------------------------------------------------------------
// Kernel 3b: 3x3 box filter (zero-padded, /9) on m -> beta_map
// ---------------------------------------------------------------------------
__global__ void k_box(const float* __restrict__ m, float* __restrict__ beta_map) {
    const int idx = blockIdx.x * 256 + threadIdx.x;
    if (idx >= NHW_) return;
    const int w = idx % W_;
    const int h = (idx / W_) % H_;
    const int n = idx / HW_;
    const float* mp = m + (size_t)n * HW_;
    float s = 0.f;
#pragma unroll
    for (int dh = 0; dh < 3; ++dh) {
        int ih = h + dh - 1;
        if (ih < 0 || ih >= H_) continue;
#pragma unroll
        for (int dw = 0; dw < 3; ++dw) {
            int iw = w + dw - 1;
            if (iw < 0 || iw >= W_) continue;
            s += mp[ih * W_ + iw];
        }
    }
    beta_map[idx] = s * (1.f / 9.f);
}

// ---------------------------------------------------------------------------
// Kernel 4: binary conv, uniform-window mapping.
// lane = cout: the 36 u64 WEIGHTS are per-lane registers, loaded once per
// block. Block processes 32 consecutive pixels; the x window is wave-uniform
// -> scalar loads (or broadcast vector loads), near-zero traffic. Row of 3
// taps x 4 words = 12 contiguous u64 in padded layout -> wide s_loads.
// Epilogue buffered in LDS [256][33] (conflict-free) then float4 writeout
// (each thread owns cout t: 32 contiguous floats = full cache lines).
// ---------------------------------------------------------------------------
__global__ void __launch_bounds__(256, 3)
k_conv(const uint64_t* __restrict__ xbits, const uint64_t* __restrict__ wbits,
       const int* __restrict__ ctab, const float* __restrict__ beta_map,
       const float* __restrict__ alpha, const float* __restrict__ bias,
       float* __restrict__ out) {
    const int t   = (int)threadIdx.x;          // cout
    const int p0  = blockIdx.x * TPX_;
    const int n   = p0 / HW_;                  // uniform (3136 % 32 == 0)
    const int hw0 = p0 - n * HW_;

    // per-lane weights: 36 u64 = 72 VGPRs, loaded once
    uint64_t wreg[36];
    {
        const uint64_t* wp = wbits + (size_t)t * 36;
#pragma unroll
        for (int i = 0; i < 36; ++i) wreg[i] = wp[i];
    }
    const float al = alpha[t];
    const float bv = bias[t];

    __shared__ float tile[256][TPX_ + 1];

    const uint64_t* xim = xbits + (size_t)n * PIMG_ * 4;

    for (int i = 0; i < TPX_; ++i) {
        const int hw = hw0 + i;                // uniform
        const int h  = hw / W_;
        const int w  = hw - h * W_;
        int acc = 0;
#pragma unroll
        for (int dh = 0; dh < 3; ++dh) {
            const uint64_t* row = xim + ((size_t)(h + dh) * PW_ + w) * 4;  // uniform
            uint64_t xs[12];
#pragma unroll
            for (int j = 0; j < 12; ++j) xs[j] = row[j];
#pragma unroll
            for (int j = 0; j < 12; ++j)
                acc += __popcll(xs[j] ^ wreg[dh * 12 + j]);
        }
        const int rowcls = (h == 0) ? 0 : ((h == H_ - 1) ? 2 : 1);
        const int colcls = (w == 0) ? 0 : ((w == W_ - 1) ? 2 : 1);
        const int corr = ctab[(rowcls * 3 + colcls) * 256 + t];
        const float bm = beta_map[p0 + i];     // uniform
        const int dot = 2304 - 2 * acc + corr;
        float o = ((float)dot + bv) * bm * al;
        tile[t][i] = fmaxf(o, 0.f);
    }
    __syncthreads();
    float* op = out + ((size_t)(n * COUT_ + t)) * HW_ + hw0;
#pragma unroll
    for (int k = 0; k < TPX_ / 4; ++k) {
        float4 v = make_float4(tile[t][4 * k], tile[t][4 * k + 1],
                               tile[t][4 * k + 2], tile[t][4 * k + 3]);
        ((float4*)op)[k] = v;
    }
}

// ---------------------------------------------------------------------------
// Workspace layout (bytes):
//   ps       @ 0        8192
//   pq       @ 8192     8192
//   a        @ 16384    1024
//   bb       @ 17408    1024
//   alpha    @ 18432    1024
//   ctab     @ 19456    9216
//   wbits    @ 28672    73728
//   xbits    @ 102400   3444736   (32 * 58*58 * 4 u64, border zeroed by memset)
//   m        @ 3547136  401408
//   beta_map @ 3948544  401408
//   total    4349952
// ---------------------------------------------------------------------------
extern "C" void kernel_launch(void* const* d_in, const int* in_sizes, int n_in,
                              void* d_out, int out_size, void* d_ws, size_t ws_size,
                              hipStream_t stream) {
    (void)in_sizes; (void)n_in; (void)out_size; (void)ws_size;
    const float* x     = (const float*)d_in[0];
    const float* gamma = (const float*)d_in[1];
    const float* betab = (const float*)d_in[2];
    const float* Wt    = (const float*)d_in[3];
    const float* b     = (const float*)d_in[4];
    float* out = (float*)d_out;

    uint8_t* base = (uint8_t*)d_ws;
    float*    ps       = (float*)(base + 0);
    float*    pq       = (float*)(base + 8192);
    float*    a        = (float*)(base + 16384);
    float*    bb       = (float*)(base + 17408);
    float*    alpha    = (float*)(base + 18432);
    int*      ctab     = (int*)(base + 19456);
    uint64_t* wbits    = (uint64_t*)(base + 28672);
    uint64_t* xbits    = (uint64_t*)(base + 102400);
    float*    m        = (float*)(base + 3547136);
    float*    beta_map = (float*)(base + 3948544);

    k_bn_partial<<<2048, 256, 0, stream>>>(x, ps, pq);
    k_bn_final<<<1, 256, 0, stream>>>(ps, pq, gamma, betab, a, bb);
    k_wpack<<<COUT_, 256, 0, stream>>>(Wt, alpha, wbits, ctab);
    hipMemsetAsync(xbits, 0, (size_t)N_ * PIMG_ * 4 * sizeof(uint64_t), stream);
    k_mpack<<<NHW_ / 64, 256, 0, stream>>>(x, a, bb, xbits, m);
    k_box<<<(NHW_ + 255) / 256, 256, 0, stream>>>(m, beta_map);
    k_conv<<<NHW_ / TPX_, 256, 0, stream>>>(xbits, wbits, ctab, beta_map, alpha, b, out);
}